// Round 6
// baseline (643.530 us; speedup 1.0000x reference)
//
#include <hip/hip_runtime.h>
#include <hip/hip_bf16.h>
#include <math.h>

#define F_IN 128
#define F_HID 64
#define F_OUT 40
#define BN_EPS 1e-5f

__device__ __forceinline__ float bflo(unsigned u) { return __uint_as_float(u << 16); }
__device__ __forceinline__ float bfhi(unsigned u) { return __uint_as_float(u & 0xffff0000u); }

// ---- in-degree histogram (int atomics, scattered) ----
__global__ void k_deg(const int* __restrict__ col, int E, int* __restrict__ deg) {
    int e = blockIdx.x * blockDim.x + threadIdx.x;
    if (e < E) atomicAdd(deg + col[e], 1);
}

// ---- segment allocation: block-level scan, ONE cursor atomic per block ----
__global__ __launch_bounds__(256) void k_offsets(
        const int* __restrict__ deg, int* __restrict__ off,
        int* __restrict__ fill, float* __restrict__ dinv,
        int* __restrict__ cursor, int n) {
    int i = blockIdx.x * 256 + threadIdx.x;
    int lane = threadIdx.x & 63, wv = threadIdx.x >> 6;
    int d = (i < n) ? deg[i] : 0;
    int scan = d;
    #pragma unroll
    for (int o = 1; o < 64; o <<= 1) {
        int t = __shfl_up(scan, o);
        if (lane >= o) scan += t;
    }
    __shared__ int wsum[4];
    if (lane == 63) wsum[wv] = scan;
    __syncthreads();
    if (threadIdx.x == 0) {
        int s0 = wsum[0], s1 = wsum[1], s2 = wsum[2], s3 = wsum[3];
        int base = atomicAdd(cursor, s0 + s1 + s2 + s3);
        wsum[0] = base; wsum[1] = base + s0;
        wsum[2] = base + s0 + s1; wsum[3] = base + s0 + s1 + s2;
    }
    __syncthreads();
    if (i < n) {
        int b = wsum[wv] + scan - d;
        off[i] = b;
        fill[i] = b;
        dinv[i] = rsqrtf((float)d + 1.0f);  // +1 self-loop
    }
}

// ---- scatter src index into CSR slot (4 B/edge; weight re-derived in conv) ----
__global__ void k_edges(const int* __restrict__ row, const int* __restrict__ col,
                        int* __restrict__ fill, int* __restrict__ srcs, int E) {
    int e = blockIdx.x * blockDim.x + threadIdx.x;
    if (e >= E) return;
    int pos = atomicAdd(fill + col[e], 1);
    srcs[pos] = row[e];
}

// ---- h1 = BN(x) @ W1; lane=node, W1 rows as uniform scalar operands ----
__global__ __launch_bounds__(64) void k_gemm1(
        const float* __restrict__ x, const float* __restrict__ gamma,
        const float* __restrict__ beta, const float* __restrict__ mean,
        const float* __restrict__ var, const float* __restrict__ W1,
        __hip_bfloat16* __restrict__ h1b, int n) {
    __shared__ float xl[64 * 65];
    int lane = threadIdx.x;
    int nb = blockIdx.x * 64;
    float acc[F_HID];
    #pragma unroll
    for (int f = 0; f < F_HID; ++f) acc[f] = 0.f;
    int f4 = (lane & 15) * 4;
    int tn = lane >> 4;
    for (int ph = 0; ph < 2; ++ph) {
        int fb = ph * 64;
        float4 vr = *(const float4*)(var + fb + f4);
        float4 gm = *(const float4*)(gamma + fb + f4);
        float4 be = *(const float4*)(beta + fb + f4);
        float4 mn = *(const float4*)(mean + fb + f4);
        float sx = rsqrtf(vr.x + BN_EPS) * gm.x, tx = be.x - mn.x * sx;
        float sy = rsqrtf(vr.y + BN_EPS) * gm.y, ty = be.y - mn.y * sy;
        float sz = rsqrtf(vr.z + BN_EPS) * gm.z, tz = be.z - mn.z * sz;
        float sw = rsqrtf(vr.w + BN_EPS) * gm.w, tw = be.w - mn.w * sw;
        if (ph) __syncthreads();
        for (int it = 0; it < 16; ++it) {
            int r = it * 4 + tn;
            int node = nb + r;
            float4 v = make_float4(0.f, 0.f, 0.f, 0.f);
            if (node < n) v = *(const float4*)(x + (long)node * F_IN + fb + f4);
            int b = r * 65 + f4;
            xl[b + 0] = v.x * sx + tx;
            xl[b + 1] = v.y * sy + ty;
            xl[b + 2] = v.z * sz + tz;
            xl[b + 3] = v.w * sw + tw;
        }
        __syncthreads();
        for (int k = 0; k < 64; ++k) {
            float xv = xl[lane * 65 + k];
            const float* wr = W1 + (fb + k) * F_HID;
            #pragma unroll
            for (int f = 0; f < F_HID; ++f) acc[f] = fmaf(xv, wr[f], acc[f]);
        }
    }
    int node = nb + lane;
    if (node < n) {
        __hip_bfloat16* dst = h1b + (long)node * F_HID;
        #pragma unroll
        for (int f = 0; f < F_HID; f += 2) {
            __hip_bfloat162 pr;
            pr.x = __float2bfloat16(acc[f]);
            pr.y = __float2bfloat16(acc[f + 1]);
            *(__hip_bfloat162*)(dst + f) = pr;
        }
    }
}

// ---- conv1: 4 nodes/wave, octet gather (8 edges/dwordx4, up to 8 in flight)
//      + self + bias + relu + fused GEMM2 ----
__global__ __launch_bounds__(256) void k_conv1(
        const uint4* __restrict__ h1q, const int* __restrict__ srcs,
        const int* __restrict__ off, const int* __restrict__ endp,
        const float* __restrict__ dinv, const float* __restrict__ b1,
        const float* __restrict__ W2, __hip_bfloat162* __restrict__ h2v, int n) {
    __shared__ float sW[F_HID * F_OUT + 24];
    for (int i = threadIdx.x; i < F_HID * F_OUT + 24; i += 256)
        sW[i] = (i < F_HID * F_OUT) ? W2[i] : 0.f;
    __syncthreads();
    int lane = threadIdx.x & 63;
    int base = blockIdx.x * 16 + (threadIdx.x >> 6) * 4;   // 4 consecutive nodes/wave
    int g = lane >> 3;
    int f = lane & 7;
    int js[4], es[4];
    #pragma unroll
    for (int nn = 0; nn < 4; ++nn) {
        int node = base + nn;
        js[nn] = (node < n) ? off[node] : 0;
        es[nn] = (node < n) ? endp[node] : 0;
    }
    float a[4][8];
    #pragma unroll
    for (int nn = 0; nn < 4; ++nn)
        #pragma unroll
        for (int q = 0; q < 8; ++q) a[nn][q] = 0.f;

    while (true) {
        int cnt[4], maxc = 0;
        #pragma unroll
        for (int nn = 0; nn < 4; ++nn) {
            int c = es[nn] - js[nn];
            c = c > 64 ? 64 : c;
            cnt[nn] = c;
            maxc = c > maxc ? c : maxc;
        }
        if (maxc <= 0) break;
        int sv[4]; float wv[4];
        #pragma unroll
        for (int nn = 0; nn < 4; ++nn) {
            int srcv = 0;
            if (lane < cnt[nn]) srcv = srcs[js[nn] + lane];
            float w = dinv[srcv];                       // row 0 for idle lanes
            sv[nn] = srcv;
            wv[nn] = (lane < cnt[nn]) ? w : 0.f;        // zero-weight trick
        }
        for (int i = 0; i < maxc; i += 16) {            // 8 gathers in flight
            #pragma unroll
            for (int nn = 0; nn < 4; ++nn) {
                int  sA = __shfl(sv[nn], i + g);      float wA = __shfl(wv[nn], i + g);
                int  sB = __shfl(sv[nn], i + 8 + g);  float wB = __shfl(wv[nn], i + 8 + g);
                uint4 uA = h1q[(long)sA * 8 + f];
                uint4 uB = h1q[(long)sB * 8 + f];
                a[nn][0] = fmaf(wA, bflo(uA.x), a[nn][0]);  a[nn][1] = fmaf(wA, bfhi(uA.x), a[nn][1]);
                a[nn][2] = fmaf(wA, bflo(uA.y), a[nn][2]);  a[nn][3] = fmaf(wA, bfhi(uA.y), a[nn][3]);
                a[nn][4] = fmaf(wA, bflo(uA.z), a[nn][4]);  a[nn][5] = fmaf(wA, bfhi(uA.z), a[nn][5]);
                a[nn][6] = fmaf(wA, bflo(uA.w), a[nn][6]);  a[nn][7] = fmaf(wA, bfhi(uA.w), a[nn][7]);
                a[nn][0] = fmaf(wB, bflo(uB.x), a[nn][0]);  a[nn][1] = fmaf(wB, bfhi(uB.x), a[nn][1]);
                a[nn][2] = fmaf(wB, bflo(uB.y), a[nn][2]);  a[nn][3] = fmaf(wB, bfhi(uB.y), a[nn][3]);
                a[nn][4] = fmaf(wB, bflo(uB.z), a[nn][4]);  a[nn][5] = fmaf(wB, bfhi(uB.z), a[nn][5]);
                a[nn][6] = fmaf(wB, bflo(uB.w), a[nn][6]);  a[nn][7] = fmaf(wB, bfhi(uB.w), a[nn][7]);
            }
        }
        #pragma unroll
        for (int nn = 0; nn < 4; ++nn) js[nn] += cnt[nn];
    }
    // cross-group reduction: all lanes end with full per-feature sums
    #pragma unroll
    for (int nn = 0; nn < 4; ++nn) {
        #pragma unroll
        for (int q = 0; q < 8; ++q) {
            float t = a[nn][q];
            t += __shfl_xor(t, 8);
            t += __shfl_xor(t, 16);
            t += __shfl_xor(t, 32);
            a[nn][q] = t;
        }
    }
    float4 bb0 = *(const float4*)(b1 + 8 * f);
    float4 bb1 = *(const float4*)(b1 + 8 * f + 4);
    #pragma unroll
    for (int nn = 0; nn < 4; ++nn) {
        int node = base + nn;
        int nodec = node < n ? node : 0;
        float d = dinv[nodec], dd = d * d;
        uint4 us = h1q[(long)nodec * 8 + f];
        a[nn][0] = fmaxf(d * a[nn][0] + dd * bflo(us.x) + bb0.x, 0.f);
        a[nn][1] = fmaxf(d * a[nn][1] + dd * bfhi(us.x) + bb0.y, 0.f);
        a[nn][2] = fmaxf(d * a[nn][2] + dd * bflo(us.y) + bb0.z, 0.f);
        a[nn][3] = fmaxf(d * a[nn][3] + dd * bfhi(us.y) + bb0.w, 0.f);
        a[nn][4] = fmaxf(d * a[nn][4] + dd * bflo(us.z) + bb1.x, 0.f);
        a[nn][5] = fmaxf(d * a[nn][5] + dd * bfhi(us.z) + bb1.y, 0.f);
        a[nn][6] = fmaxf(d * a[nn][6] + dd * bflo(us.w) + bb1.z, 0.f);
        a[nn][7] = fmaxf(d * a[nn][7] + dd * bfhi(us.w) + bb1.w, 0.f);
    }
    // fused GEMM2 across all 4 nodes: one sW read per k
    float acc2[4] = {0.f, 0.f, 0.f, 0.f};
    #pragma unroll
    for (int k = 0; k < F_HID; ++k) {
        float wk = sW[k * F_OUT + lane];
        #pragma unroll
        for (int nn = 0; nn < 4; ++nn)
            acc2[nn] = fmaf(__shfl(a[nn][k & 7], k >> 3), wk, acc2[nn]);
    }
    #pragma unroll
    for (int nn = 0; nn < 4; ++nn) {
        int node = base + nn;
        float lo = __shfl(acc2[nn], (2 * lane) & 63);
        float hi = __shfl(acc2[nn], (2 * lane + 1) & 63);
        if (node < n && lane < 20) {
            __hip_bfloat162 pr;
            pr.x = __float2bfloat16(lo);
            pr.y = __float2bfloat16(hi);
            h2v[(long)node * 20 + lane] = pr;
        }
    }
}

// ---- conv2: 4 nodes/wave, 10-lane gather (6 edges/uint2) + self + log_softmax ----
__global__ __launch_bounds__(256) void k_conv2(
        const uint2* __restrict__ h2d, const int* __restrict__ srcs,
        const int* __restrict__ off, const int* __restrict__ endp,
        const float* __restrict__ dinv, const float* __restrict__ b2,
        float* __restrict__ out, int n) {
    int lane = threadIdx.x & 63;
    int base = blockIdx.x * 16 + (threadIdx.x >> 6) * 4;
    int g = lane / 10;              // 0..6 (lanes 60-63: g=6, zero-weight junk)
    int f = lane - g * 10;          // 0..9
    int js[4], es[4];
    #pragma unroll
    for (int nn = 0; nn < 4; ++nn) {
        int node = base + nn;
        js[nn] = (node < n) ? off[node] : 0;
        es[nn] = (node < n) ? endp[node] : 0;
    }
    float a[4][4];
    #pragma unroll
    for (int nn = 0; nn < 4; ++nn)
        #pragma unroll
        for (int q = 0; q < 4; ++q) a[nn][q] = 0.f;

    while (true) {
        int cnt[4], maxc = 0;
        #pragma unroll
        for (int nn = 0; nn < 4; ++nn) {
            int c = es[nn] - js[nn];
            c = c > 60 ? 60 : c;
            cnt[nn] = c;
            maxc = c > maxc ? c : maxc;
        }
        if (maxc <= 0) break;
        int sv[4]; float wv[4];
        #pragma unroll
        for (int nn = 0; nn < 4; ++nn) {
            int srcv = 0;
            if (lane < cnt[nn]) srcv = srcs[js[nn] + lane];
            float w = dinv[srcv];
            sv[nn] = srcv;
            wv[nn] = (lane < cnt[nn]) ? w : 0.f;
        }
        for (int i = 0; i < maxc; i += 12) {            // 8 gathers in flight
            #pragma unroll
            for (int nn = 0; nn < 4; ++nn) {
                int  sA = __shfl(sv[nn], i + g);      float wA = __shfl(wv[nn], i + g);
                int  sB = __shfl(sv[nn], i + 6 + g);  float wB = __shfl(wv[nn], i + 6 + g);
                uint2 uA = h2d[(long)sA * 10 + f];
                uint2 uB = h2d[(long)sB * 10 + f];
                a[nn][0] = fmaf(wA, bflo(uA.x), a[nn][0]);  a[nn][1] = fmaf(wA, bfhi(uA.x), a[nn][1]);
                a[nn][2] = fmaf(wA, bflo(uA.y), a[nn][2]);  a[nn][3] = fmaf(wA, bfhi(uA.y), a[nn][3]);
                a[nn][0] = fmaf(wB, bflo(uB.x), a[nn][0]);  a[nn][1] = fmaf(wB, bfhi(uB.x), a[nn][1]);
                a[nn][2] = fmaf(wB, bflo(uB.y), a[nn][2]);  a[nn][3] = fmaf(wB, bfhi(uB.y), a[nn][3]);
            }
        }
        #pragma unroll
        for (int nn = 0; nn < 4; ++nn) js[nn] += cnt[nn];
    }
    #pragma unroll
    for (int nn = 0; nn < 4; ++nn) {
        int node = base + nn;
        int nodec = node < n ? node : 0;
        // reduce over groups g=0..5 (lanes f, f+10, ..., f+50)
        float t0 = 0.f, t1 = 0.f, t2 = 0.f, t3 = 0.f;
        #pragma unroll
        for (int gg = 0; gg < 6; ++gg) {
            int src = f + 10 * gg;
            t0 += __shfl(a[nn][0], src);
            t1 += __shfl(a[nn][1], src);
            t2 += __shfl(a[nn][2], src);
            t3 += __shfl(a[nn][3], src);
        }
        float d = dinv[nodec], dd = d * d;
        uint2 us = h2d[(long)nodec * 10 + f];
        float4 bb = *(const float4*)(b2 + 4 * f);
        float v0 = d * t0 + dd * bflo(us.x) + bb.x;
        float v1 = d * t1 + dd * bfhi(us.x) + bb.y;
        float v2 = d * t2 + dd * bflo(us.y) + bb.z;
        float v3 = d * t3 + dd * bfhi(us.y) + bb.w;
        float vm = fmaxf(fmaxf(v0, v1), fmaxf(v2, v3));
        #pragma unroll
        for (int o = 32; o > 0; o >>= 1) vm = fmaxf(vm, __shfl_xor(vm, o));
        float ex = (lane < 10) ? (expf(v0 - vm) + expf(v1 - vm) + expf(v2 - vm) + expf(v3 - vm)) : 0.f;
        #pragma unroll
        for (int o = 32; o > 0; o >>= 1) ex += __shfl_xor(ex, o);
        float lse = logf(ex) + vm;
        if (node < n && lane < 10) {
            float4 o4 = make_float4(v0 - lse, v1 - lse, v2 - lse, v3 - lse);
            *(float4*)(out + (long)node * F_OUT + 4 * f) = o4;
        }
    }
}

extern "C" void kernel_launch(void* const* d_in, const int* in_sizes, int n_in,
                              void* d_out, int out_size, void* d_ws, size_t ws_size,
                              hipStream_t stream) {
    const float* x     = (const float*)d_in[0];
    const int*   ei    = (const int*)d_in[1];
    const float* gamma = (const float*)d_in[2];
    const float* beta  = (const float*)d_in[3];
    const float* rmean = (const float*)d_in[4];
    const float* rvar  = (const float*)d_in[5];
    const float* W1    = (const float*)d_in[6];
    const float* b1    = (const float*)d_in[7];
    const float* W2    = (const float*)d_in[8];
    const float* b2    = (const float*)d_in[9];
    float* out = (float*)d_out;

    int n = in_sizes[0] / F_IN;
    int E = in_sizes[1] / 2;
    const int* row = ei;       // edge_index[0] = source
    const int* col = ei + E;   // edge_index[1] = target

    int*   deg    = (int*)d_ws;
    int*   off    = deg + n;
    int*   fill   = off + n;
    float* dinv   = (float*)(fill + n);
    int*   cursor = (int*)(dinv + n);                 // 4 ints (keeps 16B alignment)
    int*   srcs   = cursor + 4;                       // E ints
    __hip_bfloat16* h1b = (__hip_bfloat16*)(srcs + E);    // n*64 bf16, 16B-aligned rows
    __hip_bfloat16* h2b = h1b + (size_t)n * F_HID;        // n*40 bf16, 8B-aligned rows

    hipMemsetAsync(deg, 0, (size_t)n * sizeof(int), stream);
    hipMemsetAsync(cursor, 0, 4 * sizeof(int), stream);

    k_deg    <<<(E + 255) / 256, 256, 0, stream>>>(col, E, deg);
    k_offsets<<<(n + 255) / 256, 256, 0, stream>>>(deg, off, fill, dinv, cursor, n);
    k_edges  <<<(E + 255) / 256, 256, 0, stream>>>(row, col, fill, srcs, E);
    // after k_edges: fill[i] == off[i] + deg[i] == segment end

    k_gemm1<<<(n + 63) / 64, 64, 0, stream>>>(x, gamma, beta, rmean, rvar, W1, h1b, n);
    k_conv1<<<(n + 15) / 16, 256, 0, stream>>>((const uint4*)h1b, srcs, off, fill,
                                               dinv, b1, W2, (__hip_bfloat162*)h2b, n);
    k_conv2<<<(n + 15) / 16, 256, 0, stream>>>((const uint2*)h2b, srcs, off, fill,
                                               dinv, b2, out, n);
}

// Round 7
// 469.850 us; speedup vs baseline: 1.3696x; 1.3696x over previous
//
#include <hip/hip_runtime.h>
#include <hip/hip_bf16.h>
#include <math.h>

#define F_IN 128
#define F_HID 64
#define F_OUT 40
#define BN_EPS 1e-5f

__device__ __forceinline__ float bflo(unsigned u) { return __uint_as_float(u << 16); }
__device__ __forceinline__ float bfhi(unsigned u) { return __uint_as_float(u & 0xffff0000u); }

// ---- in-degree histogram ----
__global__ void k_deg(const int* __restrict__ col, int E, int* __restrict__ deg) {
    int e = blockIdx.x * blockDim.x + threadIdx.x;
    if (e < E) atomicAdd(deg + col[e], 1);
}

// ---- segment allocation: block scan, one cursor atomic per block ----
__global__ __launch_bounds__(256) void k_offsets(
        const int* __restrict__ deg, int* __restrict__ off,
        int* __restrict__ fill, float* __restrict__ dinv,
        int* __restrict__ cursor, int n) {
    int i = blockIdx.x * 256 + threadIdx.x;
    int lane = threadIdx.x & 63, wv = threadIdx.x >> 6;
    int d = (i < n) ? deg[i] : 0;
    int scan = d;
    #pragma unroll
    for (int o = 1; o < 64; o <<= 1) {
        int t = __shfl_up(scan, o);
        if (lane >= o) scan += t;
    }
    __shared__ int wsum[4];
    if (lane == 63) wsum[wv] = scan;
    __syncthreads();
    if (threadIdx.x == 0) {
        int s0 = wsum[0], s1 = wsum[1], s2 = wsum[2], s3 = wsum[3];
        int base = atomicAdd(cursor, s0 + s1 + s2 + s3);
        wsum[0] = base; wsum[1] = base + s0;
        wsum[2] = base + s0 + s1; wsum[3] = base + s0 + s1 + s2;
    }
    __syncthreads();
    if (i < n) {
        int b = wsum[wv] + scan - d;
        off[i] = b;
        fill[i] = b;
        dinv[i] = rsqrtf((float)d + 1.0f);  // +1 self-loop
    }
}

// ---- scatter src index into CSR slot ----
__global__ void k_edges(const int* __restrict__ row, const int* __restrict__ col,
                        int* __restrict__ fill, int* __restrict__ srcs, int E) {
    int e = blockIdx.x * blockDim.x + threadIdx.x;
    if (e >= E) return;
    int pos = atomicAdd(fill + col[e], 1);
    srcs[pos] = row[e];
}

// ---- zero pad rows (row n of h1', h2') used by idle gather lanes ----
__global__ void k_zero(unsigned* __restrict__ h1z, unsigned* __restrict__ h2z) {
    int t = threadIdx.x;
    if (t < 32) h1z[t] = 0u;
    if (t < 20) h2z[t] = 0u;
}

// ---- h1' = dinv * (BN(x) @ W1); lane=node, W1 rows as uniform scalar operands ----
__global__ __launch_bounds__(64) void k_gemm1(
        const float* __restrict__ x, const float* __restrict__ gamma,
        const float* __restrict__ beta, const float* __restrict__ mean,
        const float* __restrict__ var, const float* __restrict__ W1,
        const float* __restrict__ dinv, __hip_bfloat16* __restrict__ h1b, int n) {
    __shared__ float xl[64 * 65];
    int lane = threadIdx.x;
    int nb = blockIdx.x * 64;
    float acc[F_HID];
    #pragma unroll
    for (int f = 0; f < F_HID; ++f) acc[f] = 0.f;
    int f4 = (lane & 15) * 4;
    int tn = lane >> 4;
    for (int ph = 0; ph < 2; ++ph) {
        int fb = ph * 64;
        float4 vr = *(const float4*)(var + fb + f4);
        float4 gm = *(const float4*)(gamma + fb + f4);
        float4 be = *(const float4*)(beta + fb + f4);
        float4 mn = *(const float4*)(mean + fb + f4);
        float sx = rsqrtf(vr.x + BN_EPS) * gm.x, tx = be.x - mn.x * sx;
        float sy = rsqrtf(vr.y + BN_EPS) * gm.y, ty = be.y - mn.y * sy;
        float sz = rsqrtf(vr.z + BN_EPS) * gm.z, tz = be.z - mn.z * sz;
        float sw = rsqrtf(vr.w + BN_EPS) * gm.w, tw = be.w - mn.w * sw;
        if (ph) __syncthreads();
        for (int it = 0; it < 16; ++it) {
            int r = it * 4 + tn;
            int node = nb + r;
            float4 v = make_float4(0.f, 0.f, 0.f, 0.f);
            if (node < n) v = *(const float4*)(x + (long)node * F_IN + fb + f4);
            int b = r * 65 + f4;
            xl[b + 0] = v.x * sx + tx;
            xl[b + 1] = v.y * sy + ty;
            xl[b + 2] = v.z * sz + tz;
            xl[b + 3] = v.w * sw + tw;
        }
        __syncthreads();
        for (int k = 0; k < 64; ++k) {
            float xv = xl[lane * 65 + k];
            const float* wr = W1 + (fb + k) * F_HID;
            #pragma unroll
            for (int f = 0; f < F_HID; ++f) acc[f] = fmaf(xv, wr[f], acc[f]);
        }
    }
    int node = nb + lane;
    if (node < n) {
        float d = dinv[node];
        __hip_bfloat16* dst = h1b + (long)node * F_HID;
        #pragma unroll
        for (int f = 0; f < F_HID; f += 2) {
            __hip_bfloat162 pr;
            pr.x = __float2bfloat16(acc[f] * d);
            pr.y = __float2bfloat16(acc[f + 1] * d);
            *(__hip_bfloat162*)(dst + f) = pr;
        }
    }
}

// ---- conv1: octet gather of pre-scaled rows + self + bias + relu -> h ----
__global__ __launch_bounds__(256) void k_conv1(
        const uint4* __restrict__ h1q, const int* __restrict__ srcs,
        const int* __restrict__ off, const int* __restrict__ endp,
        const float* __restrict__ dinv, const float* __restrict__ b1,
        uint4* __restrict__ hq, int n) {
    int lane = threadIdx.x & 63;
    int node = blockIdx.x * 4 + (threadIdx.x >> 6);
    if (node >= n) return;
    int g = lane >> 3;
    int f = lane & 7;
    int s = off[node], e = endp[node];
    float a[8];
    #pragma unroll
    for (int q = 0; q < 8; ++q) a[q] = 0.f;
    int j = s;
    while (j < e) {
        int cnt = e - j; if (cnt > 64) cnt = 64;
        int srcv = n;                        // idle lanes -> zero pad row
        if (lane < cnt) srcv = srcs[j + lane];
        for (int i = 0; i < cnt; i += 16) {  // 16 edges, 2 loads in flight
            int sA = __shfl(srcv, i + g);
            int sB = __shfl(srcv, i + 8 + g);
            uint4 uA = h1q[(long)sA * 8 + f];
            uint4 uB = h1q[(long)sB * 8 + f];
            a[0] += bflo(uA.x); a[1] += bfhi(uA.x);
            a[2] += bflo(uA.y); a[3] += bfhi(uA.y);
            a[4] += bflo(uA.z); a[5] += bfhi(uA.z);
            a[6] += bflo(uA.w); a[7] += bfhi(uA.w);
            a[0] += bflo(uB.x); a[1] += bfhi(uB.x);
            a[2] += bflo(uB.y); a[3] += bfhi(uB.y);
            a[4] += bflo(uB.z); a[5] += bfhi(uB.z);
            a[6] += bflo(uB.w); a[7] += bfhi(uB.w);
        }
        j += cnt;
    }
    // reduce over the 8 edge groups
    #pragma unroll
    for (int q = 0; q < 8; ++q) {
        float t = a[q];
        t += __shfl_xor(t, 8);
        t += __shfl_xor(t, 16);
        t += __shfl_xor(t, 32);
        a[q] = t;
    }
    float d = dinv[node];
    uint4 us = h1q[(long)node * 8 + f];      // self row (pre-scaled)
    float4 bb0 = *(const float4*)(b1 + 8 * f);
    float4 bb1 = *(const float4*)(b1 + 8 * f + 4);
    float h0 = fmaxf(d * (a[0] + bflo(us.x)) + bb0.x, 0.f);
    float h1v = fmaxf(d * (a[1] + bfhi(us.x)) + bb0.y, 0.f);
    float h2v = fmaxf(d * (a[2] + bflo(us.y)) + bb0.z, 0.f);
    float h3 = fmaxf(d * (a[3] + bfhi(us.y)) + bb0.w, 0.f);
    float h4 = fmaxf(d * (a[4] + bflo(us.z)) + bb1.x, 0.f);
    float h5 = fmaxf(d * (a[5] + bfhi(us.z)) + bb1.y, 0.f);
    float h6 = fmaxf(d * (a[6] + bflo(us.w)) + bb1.z, 0.f);
    float h7 = fmaxf(d * (a[7] + bfhi(us.w)) + bb1.w, 0.f);
    if (g == 0) {                            // 8 lanes store the 128B row
        __hip_bfloat162 p0, p1, p2, p3;
        p0.x = __float2bfloat16(h0); p0.y = __float2bfloat16(h1v);
        p1.x = __float2bfloat16(h2v); p1.y = __float2bfloat16(h3);
        p2.x = __float2bfloat16(h4); p2.y = __float2bfloat16(h5);
        p3.x = __float2bfloat16(h6); p3.y = __float2bfloat16(h7);
        uint4 o;
        o.x = *(unsigned*)&p0; o.y = *(unsigned*)&p1;
        o.z = *(unsigned*)&p2; o.w = *(unsigned*)&p3;
        hq[(long)node * 8 + f] = o;
    }
}

// ---- h2' = dinv * (h @ W2); lane=node, W2 rows as uniform scalar operands ----
__global__ __launch_bounds__(64) void k_gemm2(
        const unsigned* __restrict__ h32, const float* __restrict__ W2,
        const float* __restrict__ dinv, __hip_bfloat16* __restrict__ h2b, int n) {
    __shared__ float xl[64 * 66];            // 16.9 KB
    int lane = threadIdx.x;
    int nb = blockIdx.x * 64;
    int tn = lane >> 5;
    int q = lane & 31;
    for (int it = 0; it < 32; ++it) {
        int r = it * 2 + tn;
        int node = nb + r;
        unsigned u = 0;
        if (node < n) u = h32[(long)node * 32 + q];
        xl[r * 66 + 2 * q]     = bflo(u);
        xl[r * 66 + 2 * q + 1] = bfhi(u);
    }
    __syncthreads();
    float acc[F_OUT];
    #pragma unroll
    for (int f = 0; f < F_OUT; ++f) acc[f] = 0.f;
    for (int k = 0; k < F_HID; ++k) {
        float xv = xl[lane * 66 + k];
        const float* wr = W2 + k * F_OUT;
        #pragma unroll
        for (int f = 0; f < F_OUT; ++f) acc[f] = fmaf(xv, wr[f], acc[f]);
    }
    int node = nb + lane;
    if (node < n) {
        float d = dinv[node];
        __hip_bfloat16* dst = h2b + (long)node * F_OUT;
        #pragma unroll
        for (int f = 0; f < F_OUT; f += 2) {
            __hip_bfloat162 pr;
            pr.x = __float2bfloat16(acc[f] * d);
            pr.y = __float2bfloat16(acc[f + 1] * d);
            *(__hip_bfloat162*)(dst + f) = pr;
        }
    }
}

// ---- conv2: 10-lane gather of pre-scaled rows + self + bias + log_softmax ----
__global__ __launch_bounds__(256) void k_conv2(
        const uint2* __restrict__ h2d, const int* __restrict__ srcs,
        const int* __restrict__ off, const int* __restrict__ endp,
        const float* __restrict__ dinv, const float* __restrict__ b2,
        float* __restrict__ out, int n) {
    int lane = threadIdx.x & 63;
    int node = blockIdx.x * 4 + (threadIdx.x >> 6);
    if (node >= n) return;
    int g = lane / 10;              // 0..6 (lanes 60-63: junk group, ignored)
    int f = lane - g * 10;          // 0..9
    int s = off[node], e = endp[node];
    float a0 = 0.f, a1 = 0.f, a2 = 0.f, a3 = 0.f;
    int j = s;
    while (j < e) {
        int cnt = e - j; if (cnt > 60) cnt = 60;
        int srcv = n;
        if (lane < cnt) srcv = srcs[j + lane];
        for (int i = 0; i < cnt; i += 12) {
            int sA = __shfl(srcv, i + g);
            int sB = __shfl(srcv, i + 6 + g);
            uint2 uA = h2d[(long)sA * 10 + f];
            uint2 uB = h2d[(long)sB * 10 + f];
            a0 += bflo(uA.x); a1 += bfhi(uA.x);
            a2 += bflo(uA.y); a3 += bfhi(uA.y);
            a0 += bflo(uB.x); a1 += bfhi(uB.x);
            a2 += bflo(uB.y); a3 += bfhi(uB.y);
        }
        j += cnt;
    }
    // reduce over groups g=0..5
    float t0 = 0.f, t1 = 0.f, t2 = 0.f, t3 = 0.f;
    #pragma unroll
    for (int gg = 0; gg < 6; ++gg) {
        int src = f + 10 * gg;
        t0 += __shfl(a0, src);
        t1 += __shfl(a1, src);
        t2 += __shfl(a2, src);
        t3 += __shfl(a3, src);
    }
    float d = dinv[node];
    uint2 us = h2d[(long)node * 10 + f];
    float4 bb = *(const float4*)(b2 + 4 * f);
    float v0 = d * (t0 + bflo(us.x)) + bb.x;
    float v1 = d * (t1 + bfhi(us.x)) + bb.y;
    float v2 = d * (t2 + bflo(us.y)) + bb.z;
    float v3 = d * (t3 + bfhi(us.y)) + bb.w;
    float vm = fmaxf(fmaxf(v0, v1), fmaxf(v2, v3));
    #pragma unroll
    for (int o = 32; o > 0; o >>= 1) vm = fmaxf(vm, __shfl_xor(vm, o));
    float ex = (lane < 10) ? (expf(v0 - vm) + expf(v1 - vm) + expf(v2 - vm) + expf(v3 - vm)) : 0.f;
    #pragma unroll
    for (int o = 32; o > 0; o >>= 1) ex += __shfl_xor(ex, o);
    float lse = logf(ex) + vm;
    if (lane < 10) {
        float4 o4 = make_float4(v0 - lse, v1 - lse, v2 - lse, v3 - lse);
        *(float4*)(out + (long)node * F_OUT + 4 * f) = o4;
    }
}

extern "C" void kernel_launch(void* const* d_in, const int* in_sizes, int n_in,
                              void* d_out, int out_size, void* d_ws, size_t ws_size,
                              hipStream_t stream) {
    const float* x     = (const float*)d_in[0];
    const int*   ei    = (const int*)d_in[1];
    const float* gamma = (const float*)d_in[2];
    const float* beta  = (const float*)d_in[3];
    const float* rmean = (const float*)d_in[4];
    const float* rvar  = (const float*)d_in[5];
    const float* W1    = (const float*)d_in[6];
    const float* b1    = (const float*)d_in[7];
    const float* W2    = (const float*)d_in[8];
    const float* b2    = (const float*)d_in[9];
    float* out = (float*)d_out;

    int n = in_sizes[0] / F_IN;
    int E = in_sizes[1] / 2;
    const int* row = ei;       // edge_index[0] = source
    const int* col = ei + E;   // edge_index[1] = target

    int*   deg    = (int*)d_ws;
    int*   off    = deg + n;
    int*   fill   = off + n;
    float* dinv   = (float*)(fill + n);
    int*   cursor = (int*)(dinv + n);                 // 4 ints (16B alignment)
    int*   srcs   = cursor + 4;                       // E ints
    __hip_bfloat16* h1p = (__hip_bfloat16*)(srcs + E);    // (n+1)*64 bf16, row n = 0
    __hip_bfloat16* hb  = h1p + (size_t)(n + 1) * F_HID;  // n*64 bf16 (relu out)
    __hip_bfloat16* h2p = hb + (size_t)n * F_HID;         // (n+1)*40 bf16, row n = 0

    hipMemsetAsync(deg, 0, (size_t)n * sizeof(int), stream);
    hipMemsetAsync(cursor, 0, 4 * sizeof(int), stream);

    k_deg    <<<(E + 255) / 256, 256, 0, stream>>>(col, E, deg);
    k_offsets<<<(n + 255) / 256, 256, 0, stream>>>(deg, off, fill, dinv, cursor, n);
    k_edges  <<<(E + 255) / 256, 256, 0, stream>>>(row, col, fill, srcs, E);
    k_zero   <<<1, 64, 0, stream>>>((unsigned*)(h1p + (size_t)n * F_HID),
                                    (unsigned*)(h2p + (size_t)n * F_OUT));

    k_gemm1<<<(n + 63) / 64, 64, 0, stream>>>(x, gamma, beta, rmean, rvar, W1,
                                              dinv, h1p, n);
    k_conv1<<<(n + 3) / 4, 256, 0, stream>>>((const uint4*)h1p, srcs, off, fill,
                                             dinv, b1, (uint4*)hb, n);
    k_gemm2<<<(n + 63) / 64, 64, 0, stream>>>((const unsigned*)hb, W2, dinv, h2p, n);
    k_conv2<<<(n + 3) / 4, 256, 0, stream>>>((const uint2*)h2p, srcs, off, fill,
                                             dinv, b2, out, n);
}

// Round 8
// 404.400 us; speedup vs baseline: 1.5913x; 1.1618x over previous
//
#include <hip/hip_runtime.h>
#include <hip/hip_bf16.h>
#include <math.h>

#define F_IN 128
#define F_HID 64
#define F_OUT 40
#define BN_EPS 1e-5f

__device__ __forceinline__ float bflo(unsigned u) { return __uint_as_float(u << 16); }
__device__ __forceinline__ float bfhi(unsigned u) { return __uint_as_float(u & 0xffff0000u); }

// ---- in-degree histogram; atomic return = edge's rank within its segment ----
__global__ void k_deg(const int* __restrict__ col, int E,
                      int* __restrict__ deg, int* __restrict__ rank) {
    int e = blockIdx.x * blockDim.x + threadIdx.x;
    if (e < E) rank[e] = atomicAdd(deg + col[e], 1);
}

// ---- segment allocation: block scan, one cursor atomic per block ----
__global__ __launch_bounds__(256) void k_offsets(
        const int* __restrict__ deg, int* __restrict__ off,
        int* __restrict__ endp, float* __restrict__ dinv,
        int* __restrict__ cursor, int n) {
    int i = blockIdx.x * 256 + threadIdx.x;
    int lane = threadIdx.x & 63, wv = threadIdx.x >> 6;
    int d = (i < n) ? deg[i] : 0;
    int scan = d;
    #pragma unroll
    for (int o = 1; o < 64; o <<= 1) {
        int t = __shfl_up(scan, o);
        if (lane >= o) scan += t;
    }
    __shared__ int wsum[4];
    if (lane == 63) wsum[wv] = scan;
    __syncthreads();
    if (threadIdx.x == 0) {
        int s0 = wsum[0], s1 = wsum[1], s2 = wsum[2], s3 = wsum[3];
        int base = atomicAdd(cursor, s0 + s1 + s2 + s3);
        wsum[0] = base; wsum[1] = base + s0;
        wsum[2] = base + s0 + s1; wsum[3] = base + s0 + s1 + s2;
    }
    __syncthreads();
    if (i < n) {
        int b = wsum[wv] + scan - d;
        off[i] = b;
        endp[i] = b + d;
        dinv[i] = rsqrtf((float)d + 1.0f);  // +1 self-loop
    }
}

// ---- atomic-free CSR scatter: position fully determined by off + rank ----
__global__ void k_edges(const int* __restrict__ row, const int* __restrict__ col,
                        const int* __restrict__ off, const int* __restrict__ rank,
                        int* __restrict__ srcs, int E) {
    int e = blockIdx.x * blockDim.x + threadIdx.x;
    if (e >= E) return;
    srcs[off[col[e]] + rank[e]] = row[e];
}

// ---- zero pad rows (row n of h1', h2') used by idle gather lanes ----
__global__ void k_zero(unsigned* __restrict__ h1z, unsigned* __restrict__ h2z) {
    int t = threadIdx.x;
    if (t < 32) h1z[t] = 0u;
    if (t < 20) h2z[t] = 0u;
}

// ---- h1' = dinv * (BN(x) @ W1); lane=node, W1 rows as uniform scalar operands ----
__global__ __launch_bounds__(64) void k_gemm1(
        const float* __restrict__ x, const float* __restrict__ gamma,
        const float* __restrict__ beta, const float* __restrict__ mean,
        const float* __restrict__ var, const float* __restrict__ W1,
        const float* __restrict__ dinv, __hip_bfloat16* __restrict__ h1b, int n) {
    __shared__ float xl[64 * 65];
    int lane = threadIdx.x;
    int nb = blockIdx.x * 64;
    float acc[F_HID];
    #pragma unroll
    for (int f = 0; f < F_HID; ++f) acc[f] = 0.f;
    int f4 = (lane & 15) * 4;
    int tn = lane >> 4;
    for (int ph = 0; ph < 2; ++ph) {
        int fb = ph * 64;
        float4 vr = *(const float4*)(var + fb + f4);
        float4 gm = *(const float4*)(gamma + fb + f4);
        float4 be = *(const float4*)(beta + fb + f4);
        float4 mn = *(const float4*)(mean + fb + f4);
        float sx = rsqrtf(vr.x + BN_EPS) * gm.x, tx = be.x - mn.x * sx;
        float sy = rsqrtf(vr.y + BN_EPS) * gm.y, ty = be.y - mn.y * sy;
        float sz = rsqrtf(vr.z + BN_EPS) * gm.z, tz = be.z - mn.z * sz;
        float sw = rsqrtf(vr.w + BN_EPS) * gm.w, tw = be.w - mn.w * sw;
        if (ph) __syncthreads();
        for (int it = 0; it < 16; ++it) {
            int r = it * 4 + tn;
            int node = nb + r;
            float4 v = make_float4(0.f, 0.f, 0.f, 0.f);
            if (node < n) v = *(const float4*)(x + (long)node * F_IN + fb + f4);
            int b = r * 65 + f4;
            xl[b + 0] = v.x * sx + tx;
            xl[b + 1] = v.y * sy + ty;
            xl[b + 2] = v.z * sz + tz;
            xl[b + 3] = v.w * sw + tw;
        }
        __syncthreads();
        for (int k = 0; k < 64; ++k) {
            float xv = xl[lane * 65 + k];
            const float* wr = W1 + (fb + k) * F_HID;
            #pragma unroll
            for (int f = 0; f < F_HID; ++f) acc[f] = fmaf(xv, wr[f], acc[f]);
        }
    }
    int node = nb + lane;
    if (node < n) {
        float d = dinv[node];
        __hip_bfloat16* dst = h1b + (long)node * F_HID;
        #pragma unroll
        for (int f = 0; f < F_HID; f += 2) {
            __hip_bfloat162 pr;
            pr.x = __float2bfloat16(acc[f] * d);
            pr.y = __float2bfloat16(acc[f + 1] * d);
            *(__hip_bfloat162*)(dst + f) = pr;
        }
    }
}

// ---- conv1: group-per-node gather. 4 nodes/wave, 16 lanes/node (uint2 slot f).
//      16-edge chunks fully unrolled -> up to 16 row-loads in flight/wave.
//      No cross-lane reduction: each lane's acc[4] is complete. ----
__global__ __launch_bounds__(256, 8) void k_conv1(
        const uint2* __restrict__ h1d, const int* __restrict__ srcs,
        const int* __restrict__ off, const int* __restrict__ endp,
        const float* __restrict__ dinv, const float* __restrict__ b1,
        uint2* __restrict__ hd, int n) {
    int lane = threadIdx.x & 63;
    int g = lane >> 4;                   // node group within wave
    int f = lane & 15;                   // uint2 slot within 128B row
    int gb = g * 16;                     // shfl base for this group
    int node = blockIdx.x * 16 + (threadIdx.x >> 6) * 4 + g;
    int nodec = (node < n) ? node : n;   // pad row for OOB groups
    int j = (node < n) ? off[node] : 0;
    int e = (node < n) ? endp[node] : 0;
    float a0 = 0.f, a1 = 0.f, a2 = 0.f, a3 = 0.f;
    while (__any(j < e)) {
        int cnt = e - j;
        cnt = cnt < 0 ? 0 : (cnt > 16 ? 16 : cnt);
        int srcv = n;                    // pad row (zeroed)
        if (f < cnt) srcv = srcs[j + f];
        #pragma unroll
        for (int k = 0; k < 4; ++k) {
            int s0 = __shfl(srcv, gb + 4 * k + 0);
            int s1 = __shfl(srcv, gb + 4 * k + 1);
            int s2 = __shfl(srcv, gb + 4 * k + 2);
            int s3 = __shfl(srcv, gb + 4 * k + 3);
            uint2 u0 = h1d[(long)s0 * 16 + f];
            uint2 u1 = h1d[(long)s1 * 16 + f];
            uint2 u2 = h1d[(long)s2 * 16 + f];
            uint2 u3 = h1d[(long)s3 * 16 + f];
            a0 += bflo(u0.x); a1 += bfhi(u0.x); a2 += bflo(u0.y); a3 += bfhi(u0.y);
            a0 += bflo(u1.x); a1 += bfhi(u1.x); a2 += bflo(u1.y); a3 += bfhi(u1.y);
            a0 += bflo(u2.x); a1 += bfhi(u2.x); a2 += bflo(u2.y); a3 += bfhi(u2.y);
            a0 += bflo(u3.x); a1 += bfhi(u3.x); a2 += bflo(u3.y); a3 += bfhi(u3.y);
        }
        j += cnt;
    }
    uint2 us = h1d[(long)nodec * 16 + f];        // self row (pre-scaled)
    float d = (node < n) ? dinv[node] : 0.f;
    float4 bb = ((const float4*)b1)[f];
    float h0 = fmaxf(d * (a0 + bflo(us.x)) + bb.x, 0.f);
    float h1 = fmaxf(d * (a1 + bfhi(us.x)) + bb.y, 0.f);
    float h2 = fmaxf(d * (a2 + bflo(us.y)) + bb.z, 0.f);
    float h3 = fmaxf(d * (a3 + bfhi(us.y)) + bb.w, 0.f);
    if (node < n) {
        __hip_bfloat162 p0, p1;
        p0.x = __float2bfloat16(h0); p0.y = __float2bfloat16(h1);
        p1.x = __float2bfloat16(h2); p1.y = __float2bfloat16(h3);
        uint2 o;
        o.x = *(unsigned*)&p0; o.y = *(unsigned*)&p1;
        hd[(long)node * 16 + f] = o;             // coalesced 128B row
    }
}

// ---- h2' = dinv * (h @ W2); lane=node, W2 rows as uniform scalar operands ----
__global__ __launch_bounds__(64) void k_gemm2(
        const unsigned* __restrict__ h32, const float* __restrict__ W2,
        const float* __restrict__ dinv, __hip_bfloat16* __restrict__ h2b, int n) {
    __shared__ float xl[64 * 66];
    int lane = threadIdx.x;
    int nb = blockIdx.x * 64;
    int tn = lane >> 5;
    int q = lane & 31;
    for (int it = 0; it < 32; ++it) {
        int r = it * 2 + tn;
        int node = nb + r;
        unsigned u = 0;
        if (node < n) u = h32[(long)node * 32 + q];
        xl[r * 66 + 2 * q]     = bflo(u);
        xl[r * 66 + 2 * q + 1] = bfhi(u);
    }
    __syncthreads();
    float acc[F_OUT];
    #pragma unroll
    for (int f = 0; f < F_OUT; ++f) acc[f] = 0.f;
    for (int k = 0; k < F_HID; ++k) {
        float xv = xl[lane * 66 + k];
        const float* wr = W2 + k * F_OUT;
        #pragma unroll
        for (int f = 0; f < F_OUT; ++f) acc[f] = fmaf(xv, wr[f], acc[f]);
    }
    int node = nb + lane;
    if (node < n) {
        float d = dinv[node];
        __hip_bfloat16* dst = h2b + (long)node * F_OUT;
        #pragma unroll
        for (int f = 0; f < F_OUT; f += 2) {
            __hip_bfloat162 pr;
            pr.x = __float2bfloat16(acc[f] * d);
            pr.y = __float2bfloat16(acc[f + 1] * d);
            *(__hip_bfloat162*)(dst + f) = pr;
        }
    }
}

// ---- conv2: group-per-node gather. 6 nodes/wave, 10 lanes/node (uint2 slot).
//      10-edge chunks unrolled; per-group log_softmax. ----
__global__ __launch_bounds__(256, 8) void k_conv2(
        const uint2* __restrict__ h2d, const int* __restrict__ srcs,
        const int* __restrict__ off, const int* __restrict__ endp,
        const float* __restrict__ dinv, const float* __restrict__ b2,
        float* __restrict__ out, int n) {
    int lane = threadIdx.x & 63;
    bool lact = lane < 60;
    int g = lane / 10; if (g > 5) g = 5;     // lanes 60-63 shadow group 5
    int f = lane % 10;
    int gb = g * 10;
    int node = blockIdx.x * 24 + (threadIdx.x >> 6) * 6 + g;
    if (!lact) node = n;                     // inert lanes -> pad
    int nodec = (node < n) ? node : n;
    int j = (node < n) ? off[node] : 0;
    int e = (node < n) ? endp[node] : 0;
    float a0 = 0.f, a1 = 0.f, a2 = 0.f, a3 = 0.f;
    while (__any(j < e)) {
        int cnt = e - j;
        cnt = cnt < 0 ? 0 : (cnt > 10 ? 10 : cnt);
        int srcv = n;
        if (f < cnt && lact) srcv = srcs[j + f];
        #pragma unroll
        for (int k = 0; k < 5; ++k) {
            int s0 = __shfl(srcv, gb + 2 * k + 0);
            int s1 = __shfl(srcv, gb + 2 * k + 1);
            uint2 u0 = h2d[(long)s0 * 10 + f];
            uint2 u1 = h2d[(long)s1 * 10 + f];
            a0 += bflo(u0.x); a1 += bfhi(u0.x); a2 += bflo(u0.y); a3 += bfhi(u0.y);
            a0 += bflo(u1.x); a1 += bfhi(u1.x); a2 += bflo(u1.y); a3 += bfhi(u1.y);
        }
        j += cnt;
    }
    uint2 us = h2d[(long)nodec * 10 + f];
    float d = (node < n) ? dinv[node] : 0.f;
    float4 bb = ((const float4*)b2)[f];
    float v0 = d * (a0 + bflo(us.x)) + bb.x;
    float v1 = d * (a1 + bfhi(us.x)) + bb.y;
    float v2 = d * (a2 + bflo(us.y)) + bb.z;
    float v3 = d * (a3 + bfhi(us.y)) + bb.w;
    // per-group (10-lane) max & sum-exp over the node's 40 features
    float vloc = fmaxf(fmaxf(v0, v1), fmaxf(v2, v3));
    float vm = vloc;
    #pragma unroll
    for (int i = 0; i < 10; ++i) vm = fmaxf(vm, __shfl(vloc, gb + i));
    float exloc = expf(v0 - vm) + expf(v1 - vm) + expf(v2 - vm) + expf(v3 - vm);
    float ssum = 0.f;
    #pragma unroll
    for (int i = 0; i < 10; ++i) ssum += __shfl(exloc, gb + i);
    float lse = logf(ssum) + vm;
    if (node < n && lact) {
        float4 o4 = make_float4(v0 - lse, v1 - lse, v2 - lse, v3 - lse);
        *(float4*)(out + (long)node * F_OUT + 4 * f) = o4;
    }
}

extern "C" void kernel_launch(void* const* d_in, const int* in_sizes, int n_in,
                              void* d_out, int out_size, void* d_ws, size_t ws_size,
                              hipStream_t stream) {
    const float* x     = (const float*)d_in[0];
    const int*   ei    = (const int*)d_in[1];
    const float* gamma = (const float*)d_in[2];
    const float* beta  = (const float*)d_in[3];
    const float* rmean = (const float*)d_in[4];
    const float* rvar  = (const float*)d_in[5];
    const float* W1    = (const float*)d_in[6];
    const float* b1    = (const float*)d_in[7];
    const float* W2    = (const float*)d_in[8];
    const float* b2    = (const float*)d_in[9];
    float* out = (float*)d_out;

    int n = in_sizes[0] / F_IN;
    int E = in_sizes[1] / 2;
    const int* row = ei;       // edge_index[0] = source
    const int* col = ei + E;   // edge_index[1] = target

    int*   deg    = (int*)d_ws;
    int*   off    = deg + n;
    int*   endp   = off + n;
    float* dinv   = (float*)(endp + n);
    int*   cursor = (int*)(dinv + n);                 // 4 ints (16B alignment)
    int*   rank   = cursor + 4;                       // E ints
    int*   srcs   = rank + E;                         // E ints
    __hip_bfloat16* h1p = (__hip_bfloat16*)(srcs + E);    // (n+1)*64 bf16, row n = 0
    __hip_bfloat16* hb  = h1p + (size_t)(n + 1) * F_HID;  // n*64 bf16 (relu out)
    __hip_bfloat16* h2p = hb + (size_t)n * F_HID;         // (n+1)*40 bf16, row n = 0

    hipMemsetAsync(deg, 0, (size_t)n * sizeof(int), stream);
    hipMemsetAsync(cursor, 0, 4 * sizeof(int), stream);

    k_deg    <<<(E + 255) / 256, 256, 0, stream>>>(col, E, deg, rank);
    k_offsets<<<(n + 255) / 256, 256, 0, stream>>>(deg, off, endp, dinv, cursor, n);
    k_edges  <<<(E + 255) / 256, 256, 0, stream>>>(row, col, off, rank, srcs, E);
    k_zero   <<<1, 64, 0, stream>>>((unsigned*)(h1p + (size_t)n * F_HID),
                                    (unsigned*)(h2p + (size_t)n * F_OUT));

    k_gemm1<<<(n + 63) / 64, 64, 0, stream>>>(x, gamma, beta, rmean, rvar, W1,
                                              dinv, h1p, n);
    k_conv1<<<(n + 15) / 16, 256, 0, stream>>>((const uint2*)h1p, srcs, off, endp,
                                               dinv, b1, (uint2*)hb, n);
    k_gemm2<<<(n + 63) / 64, 64, 0, stream>>>((const unsigned*)hb, W2, dinv, h2p, n);
    k_conv2<<<(n + 23) / 24, 256, 0, stream>>>((const uint2*)h2p, srcs, off, endp,
                                               dinv, b2, out, n);
}